// Round 3
// baseline (1815.522 us; speedup 1.0000x reference)
//
#include <hip/hip_runtime.h>

typedef short s8v __attribute__((ext_vector_type(8)));
typedef float f4v __attribute__((ext_vector_type(4)));

#define MFMA16(a,b,c) __builtin_amdgcn_mfma_f32_16x16x32_bf16((a),(b),(c),0,0,0)

#define N_NODES 4096
#define N_EDGE  131072
#define ATT_SCALE 0.17677669529663687f   // 1/sqrt(32)
#define NGC2     -1.5957691216057308f    // -2*sqrt(2/pi)

// fast path (hot kernel): round-half-up, 2 VALU
__device__ __forceinline__ unsigned short f2bf(float f) {
  union { float f; unsigned u; } v; v.f = f;
  return (unsigned short)((v.u + 0x8000u) >> 16);
}
// precise path (one-time prep): RNE
__device__ __forceinline__ unsigned short f2bf_rne(float f) {
  union { float f; unsigned u; } v; v.f = f;
  unsigned r = v.u + 0x7fffu + ((v.u >> 16) & 1u);
  return (unsigned short)(r >> 16);
}
__device__ __forceinline__ float bf2f(short s) {
  union { unsigned u; float f; } v;
  v.u = ((unsigned)(unsigned short)s) << 16;
  return v.f;
}
__device__ __forceinline__ int iclamp(int v, int lo, int hi) {
  return v < lo ? lo : (v > hi ? hi : v);
}

// ---------------- prep kernels ----------------

__global__ void k_tr(const float* __restrict__ src, short* __restrict__ dst,
                     int L, int K, int N) {
  int idx = blockIdx.x * 256 + threadIdx.x;
  int tot = L * K * N;
  if (idx >= tot) return;
  int l = idx / (K * N);
  int r = idx - l * (K * N);
  int k = r / N;
  int n = r - k * N;
  dst[l * K * N + n * K + k] = (short)f2bf_rne(src[idx]);
}

__global__ void k_tabs(const float* __restrict__ cart, const float* __restrict__ cemb,
                       const float* __restrict__ nemb, const float* __restrict__ comp,
                       float* __restrict__ tabs) {
  int idx = blockIdx.x * 256 + threadIdx.x;
  if (idx >= 1408) return;
  float s = 0.f;
  if (idx < 384) {
    int i = idx >> 7, d = idx & 127;
    for (int j = 0; j < 128; ++j) s += cart[i * 128 + j] * comp[j * 128 + d];
  } else if (idx < 896) {
    int i2 = idx - 384; int sp = i2 >> 7, d = i2 & 127;
    for (int j = 0; j < 128; ++j) s += cemb[sp * 128 + j] * comp[(128 + j) * 128 + d];
  } else {
    int i2 = idx - 896; int sp = i2 >> 7, d = i2 & 127;
    for (int j = 0; j < 128; ++j) s += nemb[sp * 128 + j] * comp[(256 + j) * 128 + d];
  }
  tabs[idx] = s;
}

__global__ void k_rm(const float* __restrict__ ev, const int* __restrict__ centers,
                     const int* __restrict__ nef2, float* __restrict__ rm) {
  int e = blockIdx.x * 256 + threadIdx.x;
  if (e >= N_EDGE) return;
  float x = ev[e*3], y = ev[e*3+1], z = ev[e*3+2];
  float r = sqrtf(x*x + y*y + z*z);
  float rad;
  if (r < 3.0f)      rad = 1.0f;
  else if (r < 5.0f) rad = 0.5f * (cosf(3.14159265358979f * (r - 3.0f) * 0.5f) + 1.0f);
  else               rad = 0.0f;
  int c  = iclamp(centers[e], 0, N_NODES - 1);
  int rk = iclamp(nef2[e], 0, 63);
  rm[c * 64 + rk] = rad;
}

__global__ __launch_bounds__(256) void k_enc(
    const float* __restrict__ ev, const int* __restrict__ nef,
    const int* __restrict__ centers, const int* __restrict__ neighbors,
    const int* __restrict__ species, const float* __restrict__ tabs,
    short* __restrict__ feat) {
  int n = blockIdx.x, t = threadIdx.x, j = t >> 2, qq = t & 3;
  int e = iclamp(nef[n * 64 + j], 0, N_EDGE - 1);
  float e0 = ev[e*3], e1 = ev[e*3+1], e2 = ev[e*3+2];
  int nc = iclamp(centers[e],   0, N_NODES - 1);
  int nn = iclamp(neighbors[e], 0, N_NODES - 1);
  int sc = iclamp(species[nc], 0, 3), sn = iclamp(species[nn], 0, 3);
  const float* m0 = tabs + qq*32;
  const float* m1 = tabs + 128 + qq*32;
  const float* m2 = tabs + 256 + qq*32;
  const float* tc = tabs + 384 + sc*128 + qq*32;
  const float* tn = tabs + 896 + sn*128 + qq*32;
  short* o = feat + ((size_t)(n*64 + j))*128 + qq*32;
  #pragma unroll
  for (int i = 0; i < 32; i += 2) {
    float a = e0*m0[i]   + e1*m1[i]   + e2*m2[i]   + tc[i]   + tn[i];
    float b = e0*m0[i+1] + e1*m1[i+1] + e2*m2[i+1] + tc[i+1] + tn[i+1];
    *(unsigned*)(o + i) = (unsigned)f2bf_rne(a) | ((unsigned)f2bf_rne(b) << 16);
  }
}

// ---------------- fused transformer (2 layers), static 69KB LDS ----------------
// block = one node; 4 waves partition columns. Residual x in f32 regs.
// MFMA C-layout: row = mt*16+quad*4+reg, col = wid*32+nt*16+l4.
// LDS: hb (17408) | kb (17408) | vtb (18432, red 2048 aliased at base) | qb (17408).
// Total 70656 B; at (256,2) the LDS budget is 80KB/block -> qb is free.
// R12 evidence: spill eliminated (WRITE 254->65.5MB) with dur UNCHANGED (733us)
// -> spill was L2-absorbed, off critical path. Plateau = issue/latency:
// MfmaUtil 13%, VALUBusy 32%, ~40% of cycles pure dependency stall inside each
// wave's serial program. The unroll-1 fences (installed for the 84-reg cap)
// are now blocking ILP that the 256-reg budget can afford.
// R13: (a) dedicated qb kills the hb-overwrite hazard -> both per-hh QKV
// barriers deleted; (b) QKV j-loop unroll 2 -> j+1 weight loads prefetch under
// j's MFMAs; (c) attention m2 pipelines unrolled (bk CSEs across them);
// (d) MLP G-write hh unrolled.
// Predicted: VGPR 108->~150, WRITE stays ~65MB (>=100MB => re-spilled, back
// off), MfmaUtil 13->16-19, dur 733 -> ~590-650us.
// Falsifier: <3% dur change, no spill -> intra-wave ILP not the stall ->
// plateau is barrier/inter-wave structural.

__device__ __forceinline__ void ln_sub(float (&xr)[4][2][4],
                                       const float* __restrict__ gw, const float* __restrict__ gb,
                                       float* red, short* hb, int wid, int quad, int l4) {
  #pragma unroll
  for (int mt = 0; mt < 4; ++mt)
    #pragma unroll
    for (int reg = 0; reg < 4; ++reg) {
      float a = xr[mt][0][reg] + xr[mt][1][reg];
      float s = xr[mt][0][reg]*xr[mt][0][reg] + xr[mt][1][reg]*xr[mt][1][reg];
      #pragma unroll
      for (int m = 1; m < 16; m <<= 1) { a += __shfl_xor(a, m); s += __shfl_xor(s, m); }
      if (l4 == 0) {
        int r = mt*16 + quad*4 + reg;
        red[(wid*64 + r)*2]     = a;
        red[(wid*64 + r)*2 + 1] = s;
      }
    }
  __syncthreads();
  int tid = threadIdx.x;
  if (tid < 64) {
    float a = 0.f, s = 0.f;
    #pragma unroll
    for (int w = 0; w < 4; ++w) { a += red[(w*64 + tid)*2]; s += red[(w*64 + tid)*2 + 1]; }
    float mean = a * (1.f/128.f);
    float var  = s * (1.f/128.f) - mean*mean;
    red[tid*2]     = mean;
    red[tid*2 + 1] = rsqrtf(var + 1e-5f);
  }
  __syncthreads();
  float gv[2], bv[2];
  #pragma unroll
  for (int nt = 0; nt < 2; ++nt) { int c = wid*32 + nt*16 + l4; gv[nt] = gw[c]; bv[nt] = gb[c]; }
  #pragma unroll
  for (int mt = 0; mt < 4; ++mt)
    #pragma unroll
    for (int reg = 0; reg < 4; ++reg) {
      int r = mt*16 + quad*4 + reg;
      float mean = red[r*2], inv = red[r*2 + 1];
      #pragma unroll
      for (int nt = 0; nt < 2; ++nt) {
        float h = (xr[mt][nt][reg] - mean) * inv * gv[nt] + bv[nt];
        hb[r*136 + wid*32 + nt*16 + l4] = (short)f2bf(h);
      }
    }
  __syncthreads();
}

__global__ __launch_bounds__(256, 2) void k_tf(
    short* __restrict__ x, const float* __restrict__ rm,
    const float* __restrict__ lnw1, const float* __restrict__ lnb1,
    const short* __restrict__ qkvT, const float* __restrict__ qkvb,
    const short* __restrict__ outT, const float* __restrict__ outb,
    const float* __restrict__ lnw2, const float* __restrict__ lnb2,
    const short* __restrict__ m1T, const float* __restrict__ m1b,
    const short* __restrict__ m2T, const float* __restrict__ m2b) {
  __shared__ __align__(16) char smem[70656];
  short* hb  = (short*)smem;              // 17408 B: LN-out / P-scratch / attn-out
  short* kb  = (short*)(smem + 17408);    // 17408 B: k (intact thru attn); MLP G0
  short* vtb = (short*)(smem + 34816);    // 18432 B: V^T [feat128][key stride 72]; MLP G1
  float* red = (float*)(smem + 34816);    // 2048 B aliased at vtb base (LN phases only)
  short* qb  = (short*)(smem + 53248);    // 17408 B: q (dedicated -> no QKV barriers)

  const int tid = threadIdx.x;
  const int wid = tid >> 6;
  const int lane = tid & 63;
  const int l4 = lane & 15;
  const int quad = lane >> 4;
  const int n = blockIdx.x;

  short* xg = x + (size_t)n * 64 * 128;
  float xr[4][2][4];
  #pragma unroll
  for (int mt = 0; mt < 4; ++mt)
    #pragma unroll
    for (int nt = 0; nt < 2; ++nt)
      #pragma unroll
      for (int reg = 0; reg < 4; ++reg)
        xr[mt][nt][reg] = bf2f(xg[(mt*16 + quad*4 + reg)*128 + wid*32 + nt*16 + l4]);

  for (int l = 0; l < 2; ++l) {
    const float* g1    = lnw1 + l*128;   const float* bb1   = lnb1 + l*128;
    const short* qkvTl = qkvT + l*49152; const float* qkvbl = qkvb + l*384;
    const short* outTl = outT + l*16384; const float* outbl = outb + l*128;
    const float* g2    = lnw2 + l*128;   const float* bb2   = lnb2 + l*128;
    const short* m1Tl  = m1T + l*65536;  const float* m1bl  = m1b + l*512;
    const short* m2Tl  = m2T + l*65536;  const float* m2bl  = m2b + l*128;

    // guard red(=vtb) writes vs previous layer's MLP G1 reads
    __syncthreads();

    ln_sub(xr, g1, bb1, red, hb, wid, quad, l4);   // -> hb, trailing barrier

    // ---- QKV: barrier-free (q -> qb; hb stays intact through both halves) ----
    #pragma unroll 1
    for (int hh = 0; hh < 2; ++hh) {
      s8v af[2][4];
      #pragma unroll
      for (int m2 = 0; m2 < 2; ++m2)
        #pragma unroll
        for (int k0 = 0; k0 < 4; ++k0)
          af[m2][k0] = *(const s8v*)(hb + ((hh*2 + m2)*16 + l4)*136 + k0*32 + quad*8);

      #pragma unroll 2
      for (int j = 0; j < 6; ++j) {
        int col = wid*96 + j*16 + l4;
        s8v bf[4];
        #pragma unroll
        for (int k0 = 0; k0 < 4; ++k0)
          bf[k0] = *(const s8v*)(qkvTl + col*128 + k0*32 + quad*8);
        float bias = qkvbl[col];
        f4v acc[2];
        #pragma unroll
        for (int m2 = 0; m2 < 2; ++m2) { f4v bb = {bias,bias,bias,bias}; acc[m2] = bb; }
        #pragma unroll
        for (int k0 = 0; k0 < 4; ++k0)
          #pragma unroll
          for (int m2 = 0; m2 < 2; ++m2)
            acc[m2] = MFMA16(af[m2][k0], bf[k0], acc[m2]);
        if (col < 128) {
          #pragma unroll
          for (int m2 = 0; m2 < 2; ++m2)
            #pragma unroll
            for (int reg = 0; reg < 4; ++reg)
              qb[((hh*2+m2)*16 + quad*4 + reg)*136 + col] = (short)f2bf(acc[m2][reg] * ATT_SCALE);
        } else if (col < 256) {
          int c = col - 128;
          #pragma unroll
          for (int m2 = 0; m2 < 2; ++m2)
            #pragma unroll
            for (int reg = 0; reg < 4; ++reg)
              kb[((hh*2+m2)*16 + quad*4 + reg)*136 + c] = (short)f2bf(acc[m2][reg]);
        } else {
          int c = col - 256;
          #pragma unroll
          for (int m2 = 0; m2 < 2; ++m2)
            #pragma unroll
            for (int reg = 0; reg < 4; ++reg)
              vtb[c*72 + (hh*2+m2)*16 + quad*4 + reg] = (short)f2bf(acc[m2][reg]);
        }
      }
    }
    __syncthreads();

    // ---- attention: wave = head; zero internal barriers. m2 pipelines
    // unrolled for ILP (independent rows; bk loads CSE across them).
    // P-scratch lives in hb rows row0..row0+15 (h is dead), own col stripe.
    {
      const int h = wid;
      float rv[4];
      #pragma unroll
      for (int n2 = 0; n2 < 4; ++n2) rv[n2] = rm[n*64 + n2*16 + l4];

      #pragma unroll 1
      for (int hh = 0; hh < 2; ++hh) {
        #pragma unroll
        for (int m2 = 0; m2 < 2; ++m2) {
          const int row0 = (hh*2 + m2)*16;
          f4v S[4];
          {
            s8v aq = *(const s8v*)(qb + (row0 + l4)*136 + h*32 + quad*8);
            s8v bk0 = *(const s8v*)(kb + (      l4)*136 + h*32 + quad*8);
            s8v bk1 = *(const s8v*)(kb + (16 + l4)*136 + h*32 + quad*8);
            s8v bk2 = *(const s8v*)(kb + (32 + l4)*136 + h*32 + quad*8);
            s8v bk3 = *(const s8v*)(kb + (48 + l4)*136 + h*32 + quad*8);
            f4v zz = {0.f,0.f,0.f,0.f};
            S[0] = MFMA16(aq, bk0, zz);
            S[1] = MFMA16(aq, bk1, zz);
            S[2] = MFMA16(aq, bk2, zz);
            S[3] = MFMA16(aq, bk3, zz);
          }

          #pragma unroll
          for (int reg = 0; reg < 4; ++reg) {
            float mx = fmaxf(fmaxf(S[0][reg], S[1][reg]),
                             fmaxf(S[2][reg], S[3][reg]));
            mx = fmaxf(mx, __shfl_xor(mx, 1));
            mx = fmaxf(mx, __shfl_xor(mx, 2));
            mx = fmaxf(mx, __shfl_xor(mx, 4));
            mx = fmaxf(mx, __shfl_xor(mx, 8));
            float E = 0.f, W = 0.f;
            #pragma unroll
            for (int n2 = 0; n2 < 4; ++n2) {
              float e = __expf(S[n2][reg] - mx);
              E += e; W += e * rv[n2];
              S[n2][reg] = e * rv[n2];
            }
            E += __shfl_xor(E, 1); E += __shfl_xor(E, 2);
            E += __shfl_xor(E, 4); E += __shfl_xor(E, 8);
            W += __shfl_xor(W, 1); W += __shfl_xor(W, 2);
            W += __shfl_xor(W, 4); W += __shfl_xor(W, 8);
            float inv = __builtin_amdgcn_rcpf(W + 1e-9f * E);
            #pragma unroll
            for (int n2 = 0; n2 < 4; ++n2) S[n2][reg] *= inv;
          }

          // PV in 32-key chunks; P transposed through own hb rows
          f4v o[2];
          { f4v zz = {0.f,0.f,0.f,0.f}; o[0] = zz; o[1] = zz; }
          #pragma unroll
          for (int c = 0; c < 2; ++c) {
            #pragma unroll
            for (int n2 = 0; n2 < 2; ++n2)
              #pragma unroll
              for (int reg = 0; reg < 4; ++reg)
                hb[(row0 + quad*4 + reg)*136 + h*32 + n2*16 + l4] =
                    (short)f2bf(S[2*c + n2][reg]);
            s8v ap = *(const s8v*)(hb + (row0 + l4)*136 + h*32 + quad*8);
            #pragma unroll
            for (int nt = 0; nt < 2; ++nt) {
              s8v bv = *(const s8v*)(vtb + (h*32 + nt*16 + l4)*72 + c*32 + quad*8);
              o[nt] = MFMA16(ap, bv, o[nt]);
            }
          }
          #pragma unroll
          for (int nt = 0; nt < 2; ++nt)
            #pragma unroll
            for (int reg = 0; reg < 4; ++reg)
              hb[(row0 + quad*4 + reg)*136 + h*32 + nt*16 + l4] =
                  (short)f2bf(o[nt][reg]);
        }
      }
    }
    __syncthreads();

    // ---- output proj + residual (xr-indexed: keep unrolled) ----
    #pragma unroll
    for (int hh = 0; hh < 2; ++hh) {
      s8v ao[2][4];
      #pragma unroll
      for (int m2 = 0; m2 < 2; ++m2)
        #pragma unroll
        for (int k0 = 0; k0 < 4; ++k0)
          ao[m2][k0] = *(const s8v*)(hb + ((hh*2+m2)*16 + l4)*136 + k0*32 + quad*8);
      #pragma unroll
      for (int nt = 0; nt < 2; ++nt) {
        int c = wid*32 + nt*16 + l4;
        s8v bo[4];
        #pragma unroll
        for (int k0 = 0; k0 < 4; ++k0)
          bo[k0] = *(const s8v*)(outTl + c*128 + k0*32 + quad*8);
        float bias = outbl[c];
        #pragma unroll
        for (int m2 = 0; m2 < 2; ++m2) {
          int mt = hh*2 + m2;
          f4v a2 = {xr[mt][nt][0] + bias, xr[mt][nt][1] + bias,
                    xr[mt][nt][2] + bias, xr[mt][nt][3] + bias};
          #pragma unroll
          for (int k0 = 0; k0 < 4; ++k0)
            a2 = MFMA16(ao[m2][k0], bo[k0], a2);
          #pragma unroll
          for (int reg = 0; reg < 4; ++reg)
            xr[mt][nt][reg] = a2[reg];
        }
      }
    }

    ln_sub(xr, g2, bb2, red, hb, wid, quad, l4);   // LN2 -> hb

    // ---- MLP: weights loaded inside nt loops to cap arch pressure ----
    #pragma unroll 1
    for (int cc = 0; cc < 4; ++cc) {
      short* G = (cc & 1) ? vtb : kb;
      #pragma unroll
      for (int hh = 0; hh < 2; ++hh) {
        s8v afm[2][4];
        #pragma unroll
        for (int m2 = 0; m2 < 2; ++m2)
          #pragma unroll
          for (int k0 = 0; k0 < 4; ++k0)
            afm[m2][k0] = *(const s8v*)(hb + ((hh*2+m2)*16 + l4)*136 + k0*32 + quad*8);
        #pragma unroll
        for (int nt = 0; nt < 2; ++nt) {
          int jc = cc*128 + wid*32 + nt*16 + l4;
          s8v bm[4];
          #pragma unroll
          for (int k0 = 0; k0 < 4; ++k0)
            bm[k0] = *(const s8v*)(m1Tl + jc*128 + k0*32 + quad*8);
          float bias = m1bl[jc];
          #pragma unroll
          for (int m2 = 0; m2 < 2; ++m2) {
            f4v a2 = {bias, bias, bias, bias};
            #pragma unroll
            for (int k0 = 0; k0 < 4; ++k0)
              a2 = MFMA16(afm[m2][k0], bm[k0], a2);
            #pragma unroll
            for (int reg = 0; reg < 4; ++reg) {
              // gelu(v) = v * sigmoid(2*sqrt(2/pi)*(v + 0.044715 v^3))
              float v = a2[reg];
              float t = v * v;
              float u = fmaf(0.044715f, t, 1.0f);
              float w = v * u;
              float e = __expf(NGC2 * w);
              float gl = v * __builtin_amdgcn_rcpf(e + 1.0f);
              G[((hh*2+m2)*16 + quad*4 + reg)*136 + wid*32 + nt*16 + l4] = (short)f2bf(gl);
            }
          }
        }
      }
      __syncthreads();
      #pragma unroll
      for (int hh = 0; hh < 2; ++hh) {
        s8v at4[2][4];
        #pragma unroll
        for (int m2 = 0; m2 < 2; ++m2)
          #pragma unroll
          for (int k0 = 0; k0 < 4; ++k0)
            at4[m2][k0] = *(const s8v*)(G + ((hh*2+m2)*16 + l4)*136 + k0*32 + quad*8);
        #pragma unroll
        for (int nt = 0; nt < 2; ++nt) {
          int c = wid*32 + nt*16 + l4;
          s8v b2f[4];
          #pragma unroll
          for (int k0 = 0; k0 < 4; ++k0)
            b2f[k0] = *(const s8v*)(m2Tl + c*512 + cc*128 + k0*32 + quad*8);
          #pragma unroll
          for (int m2 = 0; m2 < 2; ++m2) {
            int mt = hh*2 + m2;
            f4v a2 = {xr[mt][nt][0], xr[mt][nt][1], xr[mt][nt][2], xr[mt][nt][3]};
            #pragma unroll
            for (int k0 = 0; k0 < 4; ++k0)
              a2 = MFMA16(at4[m2][k0], b2f[k0], a2);
            #pragma unroll
            for (int reg = 0; reg < 4; ++reg)
              xr[mt][nt][reg] = a2[reg];
          }
        }
      }
    }
    #pragma unroll
    for (int nt = 0; nt < 2; ++nt) {
      float b = m2bl[wid*32 + nt*16 + l4];
      #pragma unroll
      for (int mt = 0; mt < 4; ++mt)
        #pragma unroll
        for (int reg = 0; reg < 4; ++reg)
          xr[mt][nt][reg] += b;
    }
  }

  #pragma unroll
  for (int mt = 0; mt < 4; ++mt)
    #pragma unroll
    for (int nt = 0; nt < 2; ++nt)
      #pragma unroll
      for (int reg = 0; reg < 4; ++reg)
        xg[(mt*16 + quad*4 + reg)*128 + wid*32 + nt*16 + l4] = (short)f2bf(xr[mt][nt][reg]);
}

// ---------------- gather + GNN linear (bf16 in/out) ----------------
__global__ __launch_bounds__(256) void k_gnn(
    const short* __restrict__ feat, const int* __restrict__ nef,
    const int* __restrict__ corr, const int* __restrict__ centers,
    const int* __restrict__ nef2, const short* __restrict__ gnnT,
    short* __restrict__ out) {
  __shared__ __align__(16) short Ab[64 * 264];
  int n = blockIdx.x, t = threadIdx.x;
  int wid = t >> 6, lane = t & 63, l4 = lane & 15, quad = lane >> 4;
  int j = t >> 2, qq = t & 3;
  int e  = iclamp(nef[n*64 + j], 0, N_EDGE - 1);
  int ce = iclamp(corr[e], 0, N_EDGE - 1);
  size_t r1 = ((size_t)iclamp(centers[e],  0, N_NODES-1) * 64 + iclamp(nef2[e],  0, 63)) * 128;
  size_t r2 = ((size_t)iclamp(centers[ce], 0, N_NODES-1) * 64 + iclamp(nef2[ce], 0, 63)) * 128;
  {
    const s8v* p1 = (const s8v*)(feat + r1 + qq*32);
    const s8v* p2 = (const s8v*)(feat + r2 + qq*32);
    #pragma unroll
    for (int ii = 0; ii < 4; ++ii) {
      *(s8v*)(Ab + j*264 + qq*32 + ii*8)       = p1[ii];
      *(s8v*)(Ab + j*264 + 128 + qq*32 + ii*8) = p2[ii];
    }
  }
  __syncthreads();
  f4v acc[4][2];
  #pragma unroll
  for (int mt = 0; mt < 4; ++mt)
    #pragma unroll
    for (int nt = 0; nt < 2; ++nt) { f4v zz = {0.f,0.f,0.f,0.f}; acc[mt][nt] = zz; }
  #pragma unroll
  for (int k0 = 0; k0 < 8; ++k0) {
    s8v a[4];
    #pragma unroll
    for (int mt = 0; mt < 4; ++mt)
      a[mt] = *(const s8v*)(Ab + (mt*16 + l4)*264 + k0*32 + quad*8);
    #pragma unroll
    for (int nt = 0; nt < 2; ++nt) {
      s8v b = *(const s8v*)(gnnT + (wid*32 + nt*16 + l4)*256 + k0*32 + quad*8);
      #pragma unroll
      for (int mt = 0; mt < 4; ++mt)
        acc[mt][nt] = MFMA16(a[mt], b, acc[mt][nt]);
    }
  }
  #pragma unroll
  for (int mt = 0; mt < 4; ++mt)
    #pragma unroll
    for (int nt = 0; nt < 2; ++nt)
      #pragma unroll
      for (int reg = 0; reg < 4; ++reg)
        out[((size_t)n*64 + mt*16 + quad*4 + reg)*128 + wid*32 + nt*16 + l4] =
            (short)f2bf(acc[mt][nt][reg]);
}

// ---------------- final masked sum + head ----------------
__global__ __launch_bounds__(256) void k_final(
    const short* __restrict__ feat, const short* __restrict__ buf2,
    const float* __restrict__ rm, const float* __restrict__ lastw,
    const float* __restrict__ compw, const int* __restrict__ species,
    float* __restrict__ out) {
  __shared__ float part[4];
  int n = blockIdx.x, t = threadIdx.x;
  int wid = t >> 6, lane = t & 63;
  int j = t >> 2, qq = t & 3;
  size_t base = ((size_t)n*64 + j)*128 + qq*32;
  float s = 0.f;
  #pragma unroll
  for (int i = 0; i < 32; ++i)
    s += (bf2f(feat[base + i]) + bf2f(buf2[base + i])) * lastw[qq*32 + i];
  s += __shfl_xor(s, 1);
  s += __shfl_xor(s, 2);
  float v = (qq == 0) ? s * rm[n*64 + j] : 0.f;
  v += __shfl_xor(v, 4);  v += __shfl_xor(v, 8);
  v += __shfl_xor(v, 16); v += __shfl_xor(v, 32);
  if (lane == 0) part[wid] = v;
  __syncthreads();
  if (t == 0) out[n] = part[0] + part[1] + part[2] + part[3]
                       + compw[iclamp(species[n], 0, 3)];
}

// ---------------- host ----------------

extern "C" void kernel_launch(void* const* d_in, const int* in_sizes, int n_in,
                              void* d_out, int out_size, void* d_ws, size_t ws_size,
                              hipStream_t stream) {
  const float* ev      = (const float*)d_in[0];
  const float* cart    = (const float*)d_in[1];
  const float* cemb    = (const float*)d_in[2];
  const float* nemb    = (const float*)d_in[3];
  const float* comp    = (const float*)d_in[4];
  const float* gnnw    = (const float*)d_in[5];
  const float* lastw   = (const float*)d_in[6];
  const float* compw   = (const float*)d_in[7];
  const int*   species = (const int*)d_in[8];
  const int*   centers = (const int*)d_in[9];
  const int*   neighbors = (const int*)d_in[10];
  const int*   nef     = (const int*)d_in[11];
  /* d_in[12] = nef_mask: unused (masked slots are provably inert) */
  const int*   nef2    = (const int*)d_in[13];
  const int*   corr    = (const int*)d_in[14];

  // workspace layout (bytes)
  const size_t OFF_RM   = 0;           // 1,048,576
  const size_t OFF_FEAT = 1048576;     // 67,108,864 (bf16)
  const size_t OFF_BUF2 = 68157440;    // 67,108,864 (bf16)
  const size_t OFF_TABS = 135266304;   // 5,632
  const size_t OFF_WBF  = 135271936;   // 1,638,400
  const size_t NEED     = 136910336;
  if (ws_size < NEED) return;  // insufficient scratch: fail cleanly, not a fault

  char* ws = (char*)d_ws;
  float* rm   = (float*)(ws + OFF_RM);
  short* feat = (short*)(ws + OFF_FEAT);
  short* buf2 = (short*)(ws + OFF_BUF2);
  float* tabs = (float*)(ws + OFF_TABS);
  short* wbf  = (short*)(ws + OFF_WBF);

  short* t0q  = wbf + 0;       // 2x(384x128)
  short* t0o  = wbf + 98304;   // 2x(128x128)
  short* t0m1 = wbf + 131072;  // 2x(512x128)
  short* t0m2 = wbf + 262144;  // 2x(128x512)
  short* t1q  = wbf + 393216;
  short* t1o  = wbf + 491520;
  short* t1m1 = wbf + 524288;
  short* t1m2 = wbf + 655360;
  short* gnnT = wbf + 786432;  // 128x256

  hipMemsetAsync(rm, 0, 4096*64*sizeof(float), stream);

  k_tr<<<384, 256, 0, stream>>>((const float*)d_in[17], t0q,  2, 128, 384);
  k_tr<<<128, 256, 0, stream>>>((const float*)d_in[19], t0o,  2, 128, 128);
  k_tr<<<512, 256, 0, stream>>>((const float*)d_in[23], t0m1, 2, 128, 512);
  k_tr<<<512, 256, 0, stream>>>((const float*)d_in[25], t0m2, 2, 512, 128);
  k_tr<<<384, 256, 0, stream>>>((const float*)d_in[29], t1q,  2, 128, 384);
  k_tr<<<128, 256, 0, stream>>>((const float*)d_in[31], t1o,  2, 128, 128);
  k_tr<<<512, 256, 0, stream>>>((const float*)d_in[35], t1m1, 2, 128, 512);
  k_tr<<<512, 256, 0, stream>>>((const float*)d_in[37], t1m2, 2, 512, 128);
  k_tr<<<128, 256, 0, stream>>>(gnnw, gnnT, 1, 256, 128);
  k_tabs<<<6, 256, 0, stream>>>(cart, cemb, nemb, comp, tabs);
  k_rm<<<512, 256, 0, stream>>>(ev, centers, nef2, rm);
  k_enc<<<4096, 256, 0, stream>>>(ev, nef, centers, neighbors, species, tabs, feat);

  k_tf<<<4096, 256, 0, stream>>>(feat, rm,
      (const float*)d_in[15], (const float*)d_in[16], t0q, (const float*)d_in[18],
      t0o, (const float*)d_in[20], (const float*)d_in[21], (const float*)d_in[22],
      t0m1, (const float*)d_in[24], t0m2, (const float*)d_in[26]);

  k_gnn<<<4096, 256, 0, stream>>>(feat, nef, corr, centers, nef2, gnnT, buf2);

  k_tf<<<4096, 256, 0, stream>>>(buf2, rm,
      (const float*)d_in[27], (const float*)d_in[28], t1q, (const float*)d_in[30],
      t1o, (const float*)d_in[32], (const float*)d_in[33], (const float*)d_in[34],
      t1m1, (const float*)d_in[36], t1m2, (const float*)d_in[38]);

  k_final<<<4096, 256, 0, stream>>>(feat, buf2, rm, lastw, compw, species, (float*)d_out);
}

// Round 4
// 1814.641 us; speedup vs baseline: 1.0005x; 1.0005x over previous
//
#include <hip/hip_runtime.h>

typedef short s8v __attribute__((ext_vector_type(8)));
typedef float f4v __attribute__((ext_vector_type(4)));

#define MFMA16(a,b,c) __builtin_amdgcn_mfma_f32_16x16x32_bf16((a),(b),(c),0,0,0)

#define N_NODES 4096
#define N_EDGE  131072
#define ATT_SCALE 0.17677669529663687f   // 1/sqrt(32)
#define NGC2     -1.5957691216057308f    // -2*sqrt(2/pi)

// fast path (hot kernel): round-half-up, 2 VALU
__device__ __forceinline__ unsigned short f2bf(float f) {
  union { float f; unsigned u; } v; v.f = f;
  return (unsigned short)((v.u + 0x8000u) >> 16);
}
// precise path (one-time prep): RNE
__device__ __forceinline__ unsigned short f2bf_rne(float f) {
  union { float f; unsigned u; } v; v.f = f;
  unsigned r = v.u + 0x7fffu + ((v.u >> 16) & 1u);
  return (unsigned short)(r >> 16);
}
__device__ __forceinline__ float bf2f(short s) {
  union { unsigned u; float f; } v;
  v.u = ((unsigned)(unsigned short)s) << 16;
  return v.f;
}
__device__ __forceinline__ int iclamp(int v, int lo, int hi) {
  return v < lo ? lo : (v > hi ? hi : v);
}

// ---------------- prep kernels ----------------

__global__ void k_tr(const float* __restrict__ src, short* __restrict__ dst,
                     int L, int K, int N) {
  int idx = blockIdx.x * 256 + threadIdx.x;
  int tot = L * K * N;
  if (idx >= tot) return;
  int l = idx / (K * N);
  int r = idx - l * (K * N);
  int k = r / N;
  int n = r - k * N;
  dst[l * K * N + n * K + k] = (short)f2bf_rne(src[idx]);
}

__global__ void k_tabs(const float* __restrict__ cart, const float* __restrict__ cemb,
                       const float* __restrict__ nemb, const float* __restrict__ comp,
                       float* __restrict__ tabs) {
  int idx = blockIdx.x * 256 + threadIdx.x;
  if (idx >= 1408) return;
  float s = 0.f;
  if (idx < 384) {
    int i = idx >> 7, d = idx & 127;
    for (int j = 0; j < 128; ++j) s += cart[i * 128 + j] * comp[j * 128 + d];
  } else if (idx < 896) {
    int i2 = idx - 384; int sp = i2 >> 7, d = i2 & 127;
    for (int j = 0; j < 128; ++j) s += cemb[sp * 128 + j] * comp[(128 + j) * 128 + d];
  } else {
    int i2 = idx - 896; int sp = i2 >> 7, d = i2 & 127;
    for (int j = 0; j < 128; ++j) s += nemb[sp * 128 + j] * comp[(256 + j) * 128 + d];
  }
  tabs[idx] = s;
}

__global__ void k_rm(const float* __restrict__ ev, const int* __restrict__ centers,
                     const int* __restrict__ nef2, float* __restrict__ rm) {
  int e = blockIdx.x * 256 + threadIdx.x;
  if (e >= N_EDGE) return;
  float x = ev[e*3], y = ev[e*3+1], z = ev[e*3+2];
  float r = sqrtf(x*x + y*y + z*z);
  float rad;
  if (r < 3.0f)      rad = 1.0f;
  else if (r < 5.0f) rad = 0.5f * (cosf(3.14159265358979f * (r - 3.0f) * 0.5f) + 1.0f);
  else               rad = 0.0f;
  int c  = iclamp(centers[e], 0, N_NODES - 1);
  int rk = iclamp(nef2[e], 0, 63);
  rm[c * 64 + rk] = rad;
}

__global__ __launch_bounds__(256) void k_enc(
    const float* __restrict__ ev, const int* __restrict__ nef,
    const int* __restrict__ centers, const int* __restrict__ neighbors,
    const int* __restrict__ species, const float* __restrict__ tabs,
    short* __restrict__ feat) {
  int n = blockIdx.x, t = threadIdx.x, j = t >> 2, qq = t & 3;
  int e = iclamp(nef[n * 64 + j], 0, N_EDGE - 1);
  float e0 = ev[e*3], e1 = ev[e*3+1], e2 = ev[e*3+2];
  int nc = iclamp(centers[e],   0, N_NODES - 1);
  int nn = iclamp(neighbors[e], 0, N_NODES - 1);
  int sc = iclamp(species[nc], 0, 3), sn = iclamp(species[nn], 0, 3);
  const float* m0 = tabs + qq*32;
  const float* m1 = tabs + 128 + qq*32;
  const float* m2 = tabs + 256 + qq*32;
  const float* tc = tabs + 384 + sc*128 + qq*32;
  const float* tn = tabs + 896 + sn*128 + qq*32;
  short* o = feat + ((size_t)(n*64 + j))*128 + qq*32;
  #pragma unroll
  for (int i = 0; i < 32; i += 2) {
    float a = e0*m0[i]   + e1*m1[i]   + e2*m2[i]   + tc[i]   + tn[i];
    float b = e0*m0[i+1] + e1*m1[i+1] + e2*m2[i+1] + tc[i+1] + tn[i+1];
    *(unsigned*)(o + i) = (unsigned)f2bf_rne(a) | ((unsigned)f2bf_rne(b) << 16);
  }
}

// ---------------- fused transformer (2 layers), 8 waves/node ----------------
// R14 restructure: block = one node, 512 threads = 8 waves, each wave owns a
// 16-col stripe (cw = wid*16 + l4). Rationale (R11-R13 evidence): kernel is
// latency-bound (MfmaUtil 13%, VALUBusy 32%, HBM 2%); spill is L2-absorbed and
// off-critical-path (R12); intra-wave ILP unrolls HURT (R13, lgkmcnt is
// queue-based -> interleaved LDS pipelines serialize). Only resident
// waves/SIMD has moved the number (3 w/SIMD = 715us beat 2 w/SIMD = 733us).
// This halves each wave's serial program and doubles TLP:
// __launch_bounds__(512,4) -> 128 regs/wave, 2 blocks/CU, 4 waves/SIMD.
// LDS unchanged 53248B: hb | kb | vtb (red 4KB aliased at vtb base).
// All pipeline loops keep unroll-1 fences (R13 lesson).
// Attention: wave = (head h = wid>>1, query-half hq = wid&1), 2x16-row
// pipelines per wave; P-scratch in own q region (rows hq*32+m2*16, cols h*32).
// Predicted: dur 733 -> ~550-620us, Occupancy 23 -> ~40, VALU 32 -> ~42,
// WRITE stays ~65MB. Falsifier: dur >= ~700us with occupancy up, no spill ->
// TLP not the lever either -> barrier-chain structural ceiling, declare.

__device__ __forceinline__ void ln_sub8(float (&xr)[4][4],
                                        const float* __restrict__ gw, const float* __restrict__ gb,
                                        float* red, short* hb, int wid, int quad, int l4, int tid) {
  #pragma unroll
  for (int mt = 0; mt < 4; ++mt)
    #pragma unroll
    for (int reg = 0; reg < 4; ++reg) {
      float a = xr[mt][reg];
      float s = a * a;
      #pragma unroll
      for (int m = 1; m < 16; m <<= 1) { a += __shfl_xor(a, m); s += __shfl_xor(s, m); }
      if (l4 == 0) {
        int r = mt*16 + quad*4 + reg;
        red[(wid*64 + r)*2]     = a;
        red[(wid*64 + r)*2 + 1] = s;
      }
    }
  __syncthreads();
  if (tid < 64) {
    float a = 0.f, s = 0.f;
    #pragma unroll
    for (int w = 0; w < 8; ++w) { a += red[(w*64 + tid)*2]; s += red[(w*64 + tid)*2 + 1]; }
    float mean = a * (1.f/128.f);
    float var  = s * (1.f/128.f) - mean*mean;
    red[tid*2]     = mean;
    red[tid*2 + 1] = rsqrtf(var + 1e-5f);
  }
  __syncthreads();
  int cw = wid*16 + l4;
  float gv = gw[cw], bvv = gb[cw];
  #pragma unroll
  for (int mt = 0; mt < 4; ++mt)
    #pragma unroll
    for (int reg = 0; reg < 4; ++reg) {
      int r = mt*16 + quad*4 + reg;
      float mean = red[r*2], inv = red[r*2 + 1];
      float h = (xr[mt][reg] - mean) * inv * gv + bvv;
      hb[r*136 + cw] = (short)f2bf(h);
    }
  __syncthreads();
}

__global__ __launch_bounds__(512, 4) void k_tf(
    short* __restrict__ x, const float* __restrict__ rm,
    const float* __restrict__ lnw1, const float* __restrict__ lnb1,
    const short* __restrict__ qkvT, const float* __restrict__ qkvb,
    const short* __restrict__ outT, const float* __restrict__ outb,
    const float* __restrict__ lnw2, const float* __restrict__ lnb2,
    const short* __restrict__ m1T, const float* __restrict__ m1b,
    const short* __restrict__ m2T, const float* __restrict__ m2b) {
  __shared__ __align__(16) char smem[53248];
  short* hb  = (short*)smem;              // 17408 B: LN-out / q / P-scratch / attn-out
  short* kb  = (short*)(smem + 17408);    // 17408 B: k (intact thru attn); MLP G0
  short* vtb = (short*)(smem + 34816);    // 18432 B: V^T [feat128][key stride 72]; MLP G1
  float* red = (float*)(smem + 34816);    // 4096 B aliased at vtb base (LN phases only)

  const int tid = threadIdx.x;
  const int wid = tid >> 6;
  const int lane = tid & 63;
  const int l4 = lane & 15;
  const int quad = lane >> 4;
  const int n = blockIdx.x;
  const int cw = wid*16 + l4;             // this wave's column

  short* xg = x + (size_t)n * 64 * 128;
  float xr[4][4];
  #pragma unroll
  for (int mt = 0; mt < 4; ++mt)
    #pragma unroll
    for (int reg = 0; reg < 4; ++reg)
      xr[mt][reg] = bf2f(xg[(mt*16 + quad*4 + reg)*128 + cw]);

  for (int l = 0; l < 2; ++l) {
    const float* g1    = lnw1 + l*128;   const float* bb1   = lnb1 + l*128;
    const short* qkvTl = qkvT + l*49152; const float* qkvbl = qkvb + l*384;
    const short* outTl = outT + l*16384; const float* outbl = outb + l*128;
    const float* g2    = lnw2 + l*128;   const float* bb2   = lnb2 + l*128;
    const short* m1Tl  = m1T + l*65536;  const float* m1bl  = m1b + l*512;
    const short* m2Tl  = m2T + l*65536;  const float* m2bl  = m2b + l*128;

    // guard red(=vtb) writes vs previous layer's MLP G1 reads
    __syncthreads();

    ln_sub8(xr, g1, bb1, red, hb, wid, quad, l4, tid);   // -> hb, trailing barrier

    // ---- QKV in two 32-row halves (q overwrites hb rows of its half) ----
    #pragma unroll 1
    for (int hh = 0; hh < 2; ++hh) {
      s8v af[2][4];
      #pragma unroll
      for (int m2 = 0; m2 < 2; ++m2)
        #pragma unroll
        for (int k0 = 0; k0 < 4; ++k0)
          af[m2][k0] = *(const s8v*)(hb + ((hh*2 + m2)*16 + l4)*136 + k0*32 + quad*8);
      __syncthreads();   // all waves hold this half's h rows; safe to overwrite

      #pragma unroll 1
      for (int j = 0; j < 3; ++j) {
        int col = wid*48 + j*16 + l4;
        s8v bf[4];
        #pragma unroll
        for (int k0 = 0; k0 < 4; ++k0)
          bf[k0] = *(const s8v*)(qkvTl + col*128 + k0*32 + quad*8);
        float bias = qkvbl[col];
        f4v acc[2];
        #pragma unroll
        for (int m2 = 0; m2 < 2; ++m2) { f4v bb = {bias,bias,bias,bias}; acc[m2] = bb; }
        #pragma unroll
        for (int k0 = 0; k0 < 4; ++k0)
          #pragma unroll
          for (int m2 = 0; m2 < 2; ++m2)
            acc[m2] = MFMA16(af[m2][k0], bf[k0], acc[m2]);
        if (col < 128) {
          #pragma unroll
          for (int m2 = 0; m2 < 2; ++m2)
            #pragma unroll
            for (int reg = 0; reg < 4; ++reg)
              hb[((hh*2+m2)*16 + quad*4 + reg)*136 + col] = (short)f2bf(acc[m2][reg] * ATT_SCALE);
        } else if (col < 256) {
          int c = col - 128;
          #pragma unroll
          for (int m2 = 0; m2 < 2; ++m2)
            #pragma unroll
            for (int reg = 0; reg < 4; ++reg)
              kb[((hh*2+m2)*16 + quad*4 + reg)*136 + c] = (short)f2bf(acc[m2][reg]);
        } else {
          int c = col - 256;
          #pragma unroll
          for (int m2 = 0; m2 < 2; ++m2)
            #pragma unroll
            for (int reg = 0; reg < 4; ++reg)
              vtb[c*72 + (hh*2+m2)*16 + quad*4 + reg] = (short)f2bf(acc[m2][reg]);
        }
      }
    }
    __syncthreads();

    // ---- attention: wave = (head, query-half); zero internal barriers.
    // Each wave: two 16-row pipelines over its 32 query rows. P-scratch uses
    // own q region (rows hq*32+m2*16, cols h*32..h*32+31) -> race-free.
    {
      const int h  = wid >> 1;
      const int hq = wid & 1;
      float rv[4];
      #pragma unroll
      for (int n2 = 0; n2 < 4; ++n2) rv[n2] = rm[n*64 + n2*16 + l4];

      #pragma unroll 1
      for (int m2 = 0; m2 < 2; ++m2) {
        const int row0 = hq*32 + m2*16;
        f4v S[4];
        {
          s8v aq = *(const s8v*)(hb + (row0 + l4)*136 + h*32 + quad*8);
          s8v bk0 = *(const s8v*)(kb + (      l4)*136 + h*32 + quad*8);
          s8v bk1 = *(const s8v*)(kb + (16 + l4)*136 + h*32 + quad*8);
          s8v bk2 = *(const s8v*)(kb + (32 + l4)*136 + h*32 + quad*8);
          s8v bk3 = *(const s8v*)(kb + (48 + l4)*136 + h*32 + quad*8);
          f4v zz = {0.f,0.f,0.f,0.f};
          S[0] = MFMA16(aq, bk0, zz);
          S[1] = MFMA16(aq, bk1, zz);
          S[2] = MFMA16(aq, bk2, zz);
          S[3] = MFMA16(aq, bk3, zz);
        }

        #pragma unroll
        for (int reg = 0; reg < 4; ++reg) {
          float mx = fmaxf(fmaxf(S[0][reg], S[1][reg]),
                           fmaxf(S[2][reg], S[3][reg]));
          mx = fmaxf(mx, __shfl_xor(mx, 1));
          mx = fmaxf(mx, __shfl_xor(mx, 2));
          mx = fmaxf(mx, __shfl_xor(mx, 4));
          mx = fmaxf(mx, __shfl_xor(mx, 8));
          float E = 0.f, W = 0.f;
          #pragma unroll
          for (int n2 = 0; n2 < 4; ++n2) {
            float e = __expf(S[n2][reg] - mx);
            E += e; W += e * rv[n2];
            S[n2][reg] = e * rv[n2];
          }
          E += __shfl_xor(E, 1); E += __shfl_xor(E, 2);
          E += __shfl_xor(E, 4); E += __shfl_xor(E, 8);
          W += __shfl_xor(W, 1); W += __shfl_xor(W, 2);
          W += __shfl_xor(W, 4); W += __shfl_xor(W, 8);
          float inv = __builtin_amdgcn_rcpf(W + 1e-9f * E);
          #pragma unroll
          for (int n2 = 0; n2 < 4; ++n2) S[n2][reg] *= inv;
        }

        // PV in 32-key chunks; P transposed through own hb rows (q consumed)
        f4v o[2];
        { f4v zz = {0.f,0.f,0.f,0.f}; o[0] = zz; o[1] = zz; }
        #pragma unroll
        for (int c = 0; c < 2; ++c) {
          #pragma unroll
          for (int n2 = 0; n2 < 2; ++n2)
            #pragma unroll
            for (int reg = 0; reg < 4; ++reg)
              hb[(row0 + quad*4 + reg)*136 + h*32 + n2*16 + l4] =
                  (short)f2bf(S[2*c + n2][reg]);
          s8v ap = *(const s8v*)(hb + (row0 + l4)*136 + h*32 + quad*8);
          #pragma unroll
          for (int nt = 0; nt < 2; ++nt) {
            s8v bv = *(const s8v*)(vtb + (h*32 + nt*16 + l4)*72 + c*32 + quad*8);
            o[nt] = MFMA16(ap, bv, o[nt]);
          }
        }
        #pragma unroll
        for (int nt = 0; nt < 2; ++nt)
          #pragma unroll
          for (int reg = 0; reg < 4; ++reg)
            hb[(row0 + quad*4 + reg)*136 + h*32 + nt*16 + l4] =
                (short)f2bf(o[nt][reg]);
      }
    }
    __syncthreads();

    // ---- output proj + residual ----
    {
      s8v bo[4];
      #pragma unroll
      for (int k0 = 0; k0 < 4; ++k0)
        bo[k0] = *(const s8v*)(outTl + cw*128 + k0*32 + quad*8);
      float bias = outbl[cw];
      #pragma unroll
      for (int hh = 0; hh < 2; ++hh) {
        s8v ao[2][4];
        #pragma unroll
        for (int m2 = 0; m2 < 2; ++m2)
          #pragma unroll
          for (int k0 = 0; k0 < 4; ++k0)
            ao[m2][k0] = *(const s8v*)(hb + ((hh*2+m2)*16 + l4)*136 + k0*32 + quad*8);
        #pragma unroll
        for (int m2 = 0; m2 < 2; ++m2) {
          int mt = hh*2 + m2;
          f4v a2 = {xr[mt][0] + bias, xr[mt][1] + bias,
                    xr[mt][2] + bias, xr[mt][3] + bias};
          #pragma unroll
          for (int k0 = 0; k0 < 4; ++k0)
            a2 = MFMA16(ao[m2][k0], bo[k0], a2);
          #pragma unroll
          for (int reg = 0; reg < 4; ++reg)
            xr[mt][reg] = a2[reg];
        }
      }
    }

    ln_sub8(xr, g2, bb2, red, hb, wid, quad, l4, tid);   // LN2 -> hb

    // ---- MLP: 4 column-chunks of 128; G double-buffered kb/vtb ----
    #pragma unroll 1
    for (int cc = 0; cc < 4; ++cc) {
      short* G = (cc & 1) ? vtb : kb;
      {
        int jc = cc*128 + cw;
        s8v bm[4];
        #pragma unroll
        for (int k0 = 0; k0 < 4; ++k0)
          bm[k0] = *(const s8v*)(m1Tl + jc*128 + k0*32 + quad*8);
        float bias = m1bl[jc];
        #pragma unroll 1
        for (int hh = 0; hh < 2; ++hh) {
          s8v afm[2][4];
          #pragma unroll
          for (int m2 = 0; m2 < 2; ++m2)
            #pragma unroll
            for (int k0 = 0; k0 < 4; ++k0)
              afm[m2][k0] = *(const s8v*)(hb + ((hh*2+m2)*16 + l4)*136 + k0*32 + quad*8);
          #pragma unroll
          for (int m2 = 0; m2 < 2; ++m2) {
            f4v a2 = {bias, bias, bias, bias};
            #pragma unroll
            for (int k0 = 0; k0 < 4; ++k0)
              a2 = MFMA16(afm[m2][k0], bm[k0], a2);
            #pragma unroll
            for (int reg = 0; reg < 4; ++reg) {
              // gelu(v) = v * sigmoid(2*sqrt(2/pi)*(v + 0.044715 v^3))
              float v = a2[reg];
              float t = v * v;
              float u = fmaf(0.044715f, t, 1.0f);
              float w = v * u;
              float e = __expf(NGC2 * w);
              float gl = v * __builtin_amdgcn_rcpf(e + 1.0f);
              G[((hh*2+m2)*16 + quad*4 + reg)*136 + cw] = (short)f2bf(gl);
            }
          }
        }
      }
      __syncthreads();
      {
        s8v b2f[4];
        #pragma unroll
        for (int k0 = 0; k0 < 4; ++k0)
          b2f[k0] = *(const s8v*)(m2Tl + cw*512 + cc*128 + k0*32 + quad*8);
        #pragma unroll
        for (int hh = 0; hh < 2; ++hh) {
          s8v at4[2][4];
          #pragma unroll
          for (int m2 = 0; m2 < 2; ++m2)
            #pragma unroll
            for (int k0 = 0; k0 < 4; ++k0)
              at4[m2][k0] = *(const s8v*)(G + ((hh*2+m2)*16 + l4)*136 + k0*32 + quad*8);
          #pragma unroll
          for (int m2 = 0; m2 < 2; ++m2) {
            int mt = hh*2 + m2;
            f4v a2 = {xr[mt][0], xr[mt][1], xr[mt][2], xr[mt][3]};
            #pragma unroll
            for (int k0 = 0; k0 < 4; ++k0)
              a2 = MFMA16(at4[m2][k0], b2f[k0], a2);
            #pragma unroll
            for (int reg = 0; reg < 4; ++reg)
              xr[mt][reg] = a2[reg];
          }
        }
      }
    }
    {
      float b = m2bl[cw];
      #pragma unroll
      for (int mt = 0; mt < 4; ++mt)
        #pragma unroll
        for (int reg = 0; reg < 4; ++reg)
          xr[mt][reg] += b;
    }
  }

  #pragma unroll
  for (int mt = 0; mt < 4; ++mt)
    #pragma unroll
    for (int reg = 0; reg < 4; ++reg)
      xg[(mt*16 + quad*4 + reg)*128 + cw] = (short)f2bf(xr[mt][reg]);
}

// ---------------- gather + GNN linear (bf16 in/out) ----------------
__global__ __launch_bounds__(256) void k_gnn(
    const short* __restrict__ feat, const int* __restrict__ nef,
    const int* __restrict__ corr, const int* __restrict__ centers,
    const int* __restrict__ nef2, const short* __restrict__ gnnT,
    short* __restrict__ out) {
  __shared__ __align__(16) short Ab[64 * 264];
  int n = blockIdx.x, t = threadIdx.x;
  int wid = t >> 6, lane = t & 63, l4 = lane & 15, quad = lane >> 4;
  int j = t >> 2, qq = t & 3;
  int e  = iclamp(nef[n*64 + j], 0, N_EDGE - 1);
  int ce = iclamp(corr[e], 0, N_EDGE - 1);
  size_t r1 = ((size_t)iclamp(centers[e],  0, N_NODES-1) * 64 + iclamp(nef2[e],  0, 63)) * 128;
  size_t r2 = ((size_t)iclamp(centers[ce], 0, N_NODES-1) * 64 + iclamp(nef2[ce], 0, 63)) * 128;
  {
    const s8v* p1 = (const s8v*)(feat + r1 + qq*32);
    const s8v* p2 = (const s8v*)(feat + r2 + qq*32);
    #pragma unroll
    for (int ii = 0; ii < 4; ++ii) {
      *(s8v*)(Ab + j*264 + qq*32 + ii*8)       = p1[ii];
      *(s8v*)(Ab + j*264 + 128 + qq*32 + ii*8) = p2[ii];
    }
  }
  __syncthreads();
  f4v acc[4][2];
  #pragma unroll
  for (int mt = 0; mt < 4; ++mt)
    #pragma unroll
    for (int nt = 0; nt < 2; ++nt) { f4v zz = {0.f,0.f,0.f,0.f}; acc[mt][nt] = zz; }
  #pragma unroll
  for (int k0 = 0; k0 < 8; ++k0) {
    s8v a[4];
    #pragma unroll
    for (int mt = 0; mt < 4; ++mt)
      a[mt] = *(const s8v*)(Ab + (mt*16 + l4)*264 + k0*32 + quad*8);
    #pragma unroll
    for (int nt = 0; nt < 2; ++nt) {
      s8v b = *(const s8v*)(gnnT + (wid*32 + nt*16 + l4)*256 + k0*32 + quad*8);
      #pragma unroll
      for (int mt = 0; mt < 4; ++mt)
        acc[mt][nt] = MFMA16(a[mt], b, acc[mt][nt]);
    }
  }
  #pragma unroll
  for (int mt = 0; mt < 4; ++mt)
    #pragma unroll
    for (int nt = 0; nt < 2; ++nt)
      #pragma unroll
      for (int reg = 0; reg < 4; ++reg)
        out[((size_t)n*64 + mt*16 + quad*4 + reg)*128 + wid*32 + nt*16 + l4] =
            (short)f2bf(acc[mt][nt][reg]);
}

// ---------------- final masked sum + head ----------------
__global__ __launch_bounds__(256) void k_final(
    const short* __restrict__ feat, const short* __restrict__ buf2,
    const float* __restrict__ rm, const float* __restrict__ lastw,
    const float* __restrict__ compw, const int* __restrict__ species,
    float* __restrict__ out) {
  __shared__ float part[4];
  int n = blockIdx.x, t = threadIdx.x;
  int wid = t >> 6, lane = t & 63;
  int j = t >> 2, qq = t & 3;
  size_t base = ((size_t)n*64 + j)*128 + qq*32;
  float s = 0.f;
  #pragma unroll
  for (int i = 0; i < 32; ++i)
    s += (bf2f(feat[base + i]) + bf2f(buf2[base + i])) * lastw[qq*32 + i];
  s += __shfl_xor(s, 1);
  s += __shfl_xor(s, 2);
  float v = (qq == 0) ? s * rm[n*64 + j] : 0.f;
  v += __shfl_xor(v, 4);  v += __shfl_xor(v, 8);
  v += __shfl_xor(v, 16); v += __shfl_xor(v, 32);
  if (lane == 0) part[wid] = v;
  __syncthreads();
  if (t == 0) out[n] = part[0] + part[1] + part[2] + part[3]
                       + compw[iclamp(species[n], 0, 3)];
}

// ---------------- host ----------------

extern "C" void kernel_launch(void* const* d_in, const int* in_sizes, int n_in,
                              void* d_out, int out_size, void* d_ws, size_t ws_size,
                              hipStream_t stream) {
  const float* ev      = (const float*)d_in[0];
  const float* cart    = (const float*)d_in[1];
  const float* cemb    = (const float*)d_in[2];
  const float* nemb    = (const float*)d_in[3];
  const float* comp    = (const float*)d_in[4];
  const float* gnnw    = (const float*)d_in[5];
  const float* lastw   = (const float*)d_in[6];
  const float* compw   = (const float*)d_in[7];
  const int*   species = (const int*)d_in[8];
  const int*   centers = (const int*)d_in[9];
  const int*   neighbors = (const int*)d_in[10];
  const int*   nef     = (const int*)d_in[11];
  /* d_in[12] = nef_mask: unused (masked slots are provably inert) */
  const int*   nef2    = (const int*)d_in[13];
  const int*   corr    = (const int*)d_in[14];

  // workspace layout (bytes)
  const size_t OFF_RM   = 0;           // 1,048,576
  const size_t OFF_FEAT = 1048576;     // 67,108,864 (bf16)
  const size_t OFF_BUF2 = 68157440;    // 67,108,864 (bf16)
  const size_t OFF_TABS = 135266304;   // 5,632
  const size_t OFF_WBF  = 135271936;   // 1,638,400
  const size_t NEED     = 136910336;
  if (ws_size < NEED) return;  // insufficient scratch: fail cleanly, not a fault

  char* ws = (char*)d_ws;
  float* rm   = (float*)(ws + OFF_RM);
  short* feat = (short*)(ws + OFF_FEAT);
  short* buf2 = (short*)(ws + OFF_BUF2);
  float* tabs = (float*)(ws + OFF_TABS);
  short* wbf  = (short*)(ws + OFF_WBF);

  short* t0q  = wbf + 0;       // 2x(384x128)
  short* t0o  = wbf + 98304;   // 2x(128x128)
  short* t0m1 = wbf + 131072;  // 2x(512x128)
  short* t0m2 = wbf + 262144;  // 2x(128x512)
  short* t1q  = wbf + 393216;
  short* t1o  = wbf + 491520;
  short* t1m1 = wbf + 524288;
  short* t1m2 = wbf + 655360;
  short* gnnT = wbf + 786432;  // 128x256

  hipMemsetAsync(rm, 0, 4096*64*sizeof(float), stream);

  k_tr<<<384, 256, 0, stream>>>((const float*)d_in[17], t0q,  2, 128, 384);
  k_tr<<<128, 256, 0, stream>>>((const float*)d_in[19], t0o,  2, 128, 128);
  k_tr<<<512, 256, 0, stream>>>((const float*)d_in[23], t0m1, 2, 128, 512);
  k_tr<<<512, 256, 0, stream>>>((const float*)d_in[25], t0m2, 2, 512, 128);
  k_tr<<<384, 256, 0, stream>>>((const float*)d_in[29], t1q,  2, 128, 384);
  k_tr<<<128, 256, 0, stream>>>((const float*)d_in[31], t1o,  2, 128, 128);
  k_tr<<<512, 256, 0, stream>>>((const float*)d_in[35], t1m1, 2, 128, 512);
  k_tr<<<512, 256, 0, stream>>>((const float*)d_in[37], t1m2, 2, 512, 128);
  k_tr<<<128, 256, 0, stream>>>(gnnw, gnnT, 1, 256, 128);
  k_tabs<<<6, 256, 0, stream>>>(cart, cemb, nemb, comp, tabs);
  k_rm<<<512, 256, 0, stream>>>(ev, centers, nef2, rm);
  k_enc<<<4096, 256, 0, stream>>>(ev, nef, centers, neighbors, species, tabs, feat);

  k_tf<<<4096, 512, 0, stream>>>(feat, rm,
      (const float*)d_in[15], (const float*)d_in[16], t0q, (const float*)d_in[18],
      t0o, (const float*)d_in[20], (const float*)d_in[21], (const float*)d_in[22],
      t0m1, (const float*)d_in[24], t0m2, (const float*)d_in[26]);

  k_gnn<<<4096, 256, 0, stream>>>(feat, nef, corr, centers, nef2, gnnT, buf2);

  k_tf<<<4096, 512, 0, stream>>>(buf2, rm,
      (const float*)d_in[27], (const float*)d_in[28], t1q, (const float*)d_in[30],
      t1o, (const float*)d_in[32], (const float*)d_in[33], (const float*)d_in[34],
      t1m1, (const float*)d_in[36], t1m2, (const float*)d_in[38]);

  k_final<<<4096, 256, 0, stream>>>(feat, buf2, rm, lastw, compw, species, (float*)d_out);
}

// Round 5
// 1586.565 us; speedup vs baseline: 1.1443x; 1.1438x over previous
//
#include <hip/hip_runtime.h>

typedef short s8v __attribute__((ext_vector_type(8)));
typedef float f4v __attribute__((ext_vector_type(4)));

#define MFMA16(a,b,c) __builtin_amdgcn_mfma_f32_16x16x32_bf16((a),(b),(c),0,0,0)

#define N_NODES 4096
#define N_EDGE  131072
#define ATT_SCALE 0.17677669529663687f   // 1/sqrt(32)
#define NGC2     -1.5957691216057308f    // -2*sqrt(2/pi)

// fast path (hot kernel): round-half-up, 2 VALU
__device__ __forceinline__ unsigned short f2bf(float f) {
  union { float f; unsigned u; } v; v.f = f;
  return (unsigned short)((v.u + 0x8000u) >> 16);
}
// precise path (one-time prep): RNE
__device__ __forceinline__ unsigned short f2bf_rne(float f) {
  union { float f; unsigned u; } v; v.f = f;
  unsigned r = v.u + 0x7fffu + ((v.u >> 16) & 1u);
  return (unsigned short)(r >> 16);
}
__device__ __forceinline__ float bf2f(short s) {
  union { unsigned u; float f; } v;
  v.u = ((unsigned)(unsigned short)s) << 16;
  return v.f;
}
__device__ __forceinline__ unsigned pack2(float a, float b) {
  return (unsigned)f2bf(a) | ((unsigned)f2bf(b) << 16);
}
__device__ __forceinline__ int iclamp(int v, int lo, int hi) {
  return v < lo ? lo : (v > hi ? hi : v);
}

// ---------------- prep kernels ----------------

__global__ void k_tr(const float* __restrict__ src, short* __restrict__ dst,
                     int L, int K, int N) {
  int idx = blockIdx.x * 256 + threadIdx.x;
  int tot = L * K * N;
  if (idx >= tot) return;
  int l = idx / (K * N);
  int r = idx - l * (K * N);
  int k = r / N;
  int n = r - k * N;
  dst[l * K * N + n * K + k] = (short)f2bf_rne(src[idx]);
}

__global__ void k_tabs(const float* __restrict__ cart, const float* __restrict__ cemb,
                       const float* __restrict__ nemb, const float* __restrict__ comp,
                       float* __restrict__ tabs) {
  int idx = blockIdx.x * 256 + threadIdx.x;
  if (idx >= 1408) return;
  float s = 0.f;
  if (idx < 384) {
    int i = idx >> 7, d = idx & 127;
    for (int j = 0; j < 128; ++j) s += cart[i * 128 + j] * comp[j * 128 + d];
  } else if (idx < 896) {
    int i2 = idx - 384; int sp = i2 >> 7, d = i2 & 127;
    for (int j = 0; j < 128; ++j) s += cemb[sp * 128 + j] * comp[(128 + j) * 128 + d];
  } else {
    int i2 = idx - 896; int sp = i2 >> 7, d = i2 & 127;
    for (int j = 0; j < 128; ++j) s += nemb[sp * 128 + j] * comp[(256 + j) * 128 + d];
  }
  tabs[idx] = s;
}

__global__ void k_rm(const float* __restrict__ ev, const int* __restrict__ centers,
                     const int* __restrict__ nef2, float* __restrict__ rm) {
  int e = blockIdx.x * 256 + threadIdx.x;
  if (e >= N_EDGE) return;
  float x = ev[e*3], y = ev[e*3+1], z = ev[e*3+2];
  float r = sqrtf(x*x + y*y + z*z);
  float rad;
  if (r < 3.0f)      rad = 1.0f;
  else if (r < 5.0f) rad = 0.5f * (cosf(3.14159265358979f * (r - 3.0f) * 0.5f) + 1.0f);
  else               rad = 0.0f;
  int c  = iclamp(centers[e], 0, N_NODES - 1);
  int rk = iclamp(nef2[e], 0, 63);
  rm[c * 64 + rk] = rad;
}

__global__ __launch_bounds__(256) void k_enc(
    const float* __restrict__ ev, const int* __restrict__ nef,
    const int* __restrict__ centers, const int* __restrict__ neighbors,
    const int* __restrict__ species, const float* __restrict__ tabs,
    short* __restrict__ feat) {
  int n = blockIdx.x, t = threadIdx.x, j = t >> 2, qq = t & 3;
  int e = iclamp(nef[n * 64 + j], 0, N_EDGE - 1);
  float e0 = ev[e*3], e1 = ev[e*3+1], e2 = ev[e*3+2];
  int nc = iclamp(centers[e],   0, N_NODES - 1);
  int nn = iclamp(neighbors[e], 0, N_NODES - 1);
  int sc = iclamp(species[nc], 0, 3), sn = iclamp(species[nn], 0, 3);
  const float* m0 = tabs + qq*32;
  const float* m1 = tabs + 128 + qq*32;
  const float* m2 = tabs + 256 + qq*32;
  const float* tc = tabs + 384 + sc*128 + qq*32;
  const float* tn = tabs + 896 + sn*128 + qq*32;
  short* o = feat + ((size_t)(n*64 + j))*128 + qq*32;
  #pragma unroll
  for (int i = 0; i < 32; i += 2) {
    float a = e0*m0[i]   + e1*m1[i]   + e2*m2[i]   + tc[i]   + tn[i];
    float b = e0*m0[i+1] + e1*m1[i+1] + e2*m2[i+1] + tc[i+1] + tn[i+1];
    *(unsigned*)(o + i) = (unsigned)f2bf_rne(a) | ((unsigned)f2bf_rne(b) << 16);
  }
}

// ---------------- fused transformer (2 layers), static 52KB LDS ----------------
// block = one node; 4 waves partition columns. Residual x in f32 regs.
// MFMA C-layout: row = mt*16+quad*4+reg, col = wid*32+nt*16+l4.
// LDS: hb (17408) | kb (17408) | vtb (18432, red 2048 aliased at base).
// Config scorecard (R9-R14): (256,3)+spill=715us BEST | (256,2) no-spill=733 |
// (256,2)+ILP-unrolls=807 (lgkmcnt queue serialization) | (512,4) hi-TLP=833
// (64-reg cap). Spill is L2-absorbed/off-critical-path (R12). Occupancy, ILP,
// TLP all exhausted -> remaining stall = serial in-phase dependency chains,
// dominated by softmax's 4-deep shuffle-reduce chains (12 seq DS-latencies
// per reg-path).
// R15: swapped QK^T (S = MFMA(K_frag, Q_frag), identical fragment reads, args
// swapped) -> C[key][q]: lane holds 16 keys of ONE query q=l4. Softmax: 15
// lane-local VALU + 2-deep cross-quad shuffle (masks 16,32). Per q-tile
// shuffles 48 -> 6; serial shuffle depth 12 -> 4. rv moves to quad*4+reg
// indexing (rvr[4][4]). P stored row-major per q (4 b32 stores), read back as
// PV B-fragment (same s8v pattern); V^T is the A-operand (same read); O^T
// C-layout stores transposed -> hb[q][d], downstream proj untouched.
// Predicted: dur 715 -> ~630-670us; spill returns (~250MB WRITE, benign);
// bank-conflict drop if ds_swizzle shuffles contributed (uncertain).
// Falsifier: dur within 2% of 715 -> softmax chains off-critical-path too ->
// plateau is the barrier-phase structure; attack barriers or declare.

__device__ __forceinline__ void ln_sub(float (&xr)[4][2][4],
                                       const float* __restrict__ gw, const float* __restrict__ gb,
                                       float* red, short* hb, int wid, int quad, int l4) {
  #pragma unroll
  for (int mt = 0; mt < 4; ++mt)
    #pragma unroll
    for (int reg = 0; reg < 4; ++reg) {
      float a = xr[mt][0][reg] + xr[mt][1][reg];
      float s = xr[mt][0][reg]*xr[mt][0][reg] + xr[mt][1][reg]*xr[mt][1][reg];
      #pragma unroll
      for (int m = 1; m < 16; m <<= 1) { a += __shfl_xor(a, m); s += __shfl_xor(s, m); }
      if (l4 == 0) {
        int r = mt*16 + quad*4 + reg;
        red[(wid*64 + r)*2]     = a;
        red[(wid*64 + r)*2 + 1] = s;
      }
    }
  __syncthreads();
  int tid = threadIdx.x;
  if (tid < 64) {
    float a = 0.f, s = 0.f;
    #pragma unroll
    for (int w = 0; w < 4; ++w) { a += red[(w*64 + tid)*2]; s += red[(w*64 + tid)*2 + 1]; }
    float mean = a * (1.f/128.f);
    float var  = s * (1.f/128.f) - mean*mean;
    red[tid*2]     = mean;
    red[tid*2 + 1] = rsqrtf(var + 1e-5f);
  }
  __syncthreads();
  float gv[2], bv[2];
  #pragma unroll
  for (int nt = 0; nt < 2; ++nt) { int c = wid*32 + nt*16 + l4; gv[nt] = gw[c]; bv[nt] = gb[c]; }
  #pragma unroll
  for (int mt = 0; mt < 4; ++mt)
    #pragma unroll
    for (int reg = 0; reg < 4; ++reg) {
      int r = mt*16 + quad*4 + reg;
      float mean = red[r*2], inv = red[r*2 + 1];
      #pragma unroll
      for (int nt = 0; nt < 2; ++nt) {
        float h = (xr[mt][nt][reg] - mean) * inv * gv[nt] + bv[nt];
        hb[r*136 + wid*32 + nt*16 + l4] = (short)f2bf(h);
      }
    }
  __syncthreads();
}

__global__ __launch_bounds__(256, 3) void k_tf(
    short* __restrict__ x, const float* __restrict__ rm,
    const float* __restrict__ lnw1, const float* __restrict__ lnb1,
    const short* __restrict__ qkvT, const float* __restrict__ qkvb,
    const short* __restrict__ outT, const float* __restrict__ outb,
    const float* __restrict__ lnw2, const float* __restrict__ lnb2,
    const short* __restrict__ m1T, const float* __restrict__ m1b,
    const short* __restrict__ m2T, const float* __restrict__ m2b) {
  __shared__ __align__(16) char smem[53248];
  short* hb  = (short*)smem;              // 17408 B: LN-out / q / P-scratch / attn-out
  short* kb  = (short*)(smem + 17408);    // 17408 B: k (intact thru attn); MLP G0
  short* vtb = (short*)(smem + 34816);    // 18432 B: V^T [feat128][key stride 72]; MLP G1
  float* red = (float*)(smem + 34816);    // 2048 B aliased at vtb base (LN phases only)

  const int tid = threadIdx.x;
  const int wid = tid >> 6;
  const int lane = tid & 63;
  const int l4 = lane & 15;
  const int quad = lane >> 4;
  const int n = blockIdx.x;

  short* xg = x + (size_t)n * 64 * 128;
  float xr[4][2][4];
  #pragma unroll
  for (int mt = 0; mt < 4; ++mt)
    #pragma unroll
    for (int nt = 0; nt < 2; ++nt)
      #pragma unroll
      for (int reg = 0; reg < 4; ++reg)
        xr[mt][nt][reg] = bf2f(xg[(mt*16 + quad*4 + reg)*128 + wid*32 + nt*16 + l4]);

  for (int l = 0; l < 2; ++l) {
    const float* g1    = lnw1 + l*128;   const float* bb1   = lnb1 + l*128;
    const short* qkvTl = qkvT + l*49152; const float* qkvbl = qkvb + l*384;
    const short* outTl = outT + l*16384; const float* outbl = outb + l*128;
    const float* g2    = lnw2 + l*128;   const float* bb2   = lnb2 + l*128;
    const short* m1Tl  = m1T + l*65536;  const float* m1bl  = m1b + l*512;
    const short* m2Tl  = m2T + l*65536;  const float* m2bl  = m2b + l*128;

    // guard red(=vtb) writes vs previous layer's MLP G1 reads
    __syncthreads();

    ln_sub(xr, g1, bb1, red, hb, wid, quad, l4);   // -> hb, trailing barrier

    // ---- QKV in two 32-row halves; unroll-1 fences cap register pressure ----
    #pragma unroll 1
    for (int hh = 0; hh < 2; ++hh) {
      s8v af[2][4];
      #pragma unroll
      for (int m2 = 0; m2 < 2; ++m2)
        #pragma unroll
        for (int k0 = 0; k0 < 4; ++k0)
          af[m2][k0] = *(const s8v*)(hb + ((hh*2 + m2)*16 + l4)*136 + k0*32 + quad*8);
      __syncthreads();   // all waves hold this half's h rows; safe to overwrite

      #pragma unroll 1
      for (int j = 0; j < 6; ++j) {
        int col = wid*96 + j*16 + l4;
        s8v bf[4];
        #pragma unroll
        for (int k0 = 0; k0 < 4; ++k0)
          bf[k0] = *(const s8v*)(qkvTl + col*128 + k0*32 + quad*8);
        float bias = qkvbl[col];
        f4v acc[2];
        #pragma unroll
        for (int m2 = 0; m2 < 2; ++m2) { f4v bb = {bias,bias,bias,bias}; acc[m2] = bb; }
        #pragma unroll
        for (int k0 = 0; k0 < 4; ++k0)
          #pragma unroll
          for (int m2 = 0; m2 < 2; ++m2)
            acc[m2] = MFMA16(af[m2][k0], bf[k0], acc[m2]);
        if (col < 128) {
          #pragma unroll
          for (int m2 = 0; m2 < 2; ++m2)
            #pragma unroll
            for (int reg = 0; reg < 4; ++reg)
              hb[((hh*2+m2)*16 + quad*4 + reg)*136 + col] = (short)f2bf(acc[m2][reg] * ATT_SCALE);
        } else if (col < 256) {
          int c = col - 128;
          #pragma unroll
          for (int m2 = 0; m2 < 2; ++m2)
            #pragma unroll
            for (int reg = 0; reg < 4; ++reg)
              kb[((hh*2+m2)*16 + quad*4 + reg)*136 + c] = (short)f2bf(acc[m2][reg]);
        } else {
          int c = col - 256;
          #pragma unroll
          for (int m2 = 0; m2 < 2; ++m2)
            #pragma unroll
            for (int reg = 0; reg < 4; ++reg)
              vtb[c*72 + (hh*2+m2)*16 + quad*4 + reg] = (short)f2bf(acc[m2][reg]);
        }
      }
    }
    __syncthreads();

    // ---- attention (swapped QK^T): wave = head; zero internal barriers.
    // S = MFMA(K_frag, Q_frag) -> C[key][q]: lane l4 = query, regs = 16 keys
    // (quad*4+reg per 16-key tile). Softmax: lane-local over regs + 2-deep
    // cross-quad shuffle (masks 16,32). P stored row-major per q into own hb
    // rows (q consumed), read back as PV B-fragment; V^T is the A-operand.
    // O^T C-layout -> stored transposed into hb[q][d]; proj phase unchanged.
    {
      const int h = wid;
      float rvr[4][4];
      #pragma unroll
      for (int n2 = 0; n2 < 4; ++n2)
        #pragma unroll
        for (int reg = 0; reg < 4; ++reg)
          rvr[n2][reg] = rm[n*64 + n2*16 + quad*4 + reg];

      #pragma unroll 1
      for (int qt = 0; qt < 4; ++qt) {
        const int row0 = qt*16;
        f4v S[4];
        {
          s8v bq = *(const s8v*)(hb + (row0 + l4)*136 + h*32 + quad*8);
          s8v ak0 = *(const s8v*)(kb + (      l4)*136 + h*32 + quad*8);
          s8v ak1 = *(const s8v*)(kb + (16 + l4)*136 + h*32 + quad*8);
          s8v ak2 = *(const s8v*)(kb + (32 + l4)*136 + h*32 + quad*8);
          s8v ak3 = *(const s8v*)(kb + (48 + l4)*136 + h*32 + quad*8);
          f4v zz = {0.f,0.f,0.f,0.f};
          S[0] = MFMA16(ak0, bq, zz);   // C[key][q]
          S[1] = MFMA16(ak1, bq, zz);
          S[2] = MFMA16(ak2, bq, zz);
          S[3] = MFMA16(ak3, bq, zz);
        }

        // softmax over 64 keys for query q=l4: lane-local + cross-quad
        {
          float mx = S[0][0];
          #pragma unroll
          for (int n2 = 0; n2 < 4; ++n2)
            #pragma unroll
            for (int reg = 0; reg < 4; ++reg)
              mx = fmaxf(mx, S[n2][reg]);
          mx = fmaxf(mx, __shfl_xor(mx, 16));
          mx = fmaxf(mx, __shfl_xor(mx, 32));
          float E = 0.f, W = 0.f;
          #pragma unroll
          for (int n2 = 0; n2 < 4; ++n2)
            #pragma unroll
            for (int reg = 0; reg < 4; ++reg) {
              float e = __expf(S[n2][reg] - mx);
              E += e; W += e * rvr[n2][reg];
              S[n2][reg] = e * rvr[n2][reg];
            }
          E += __shfl_xor(E, 16); E += __shfl_xor(E, 32);
          W += __shfl_xor(W, 16); W += __shfl_xor(W, 32);
          float inv = __builtin_amdgcn_rcpf(W + 1e-9f * E);
          #pragma unroll
          for (int n2 = 0; n2 < 4; ++n2)
            #pragma unroll
            for (int reg = 0; reg < 4; ++reg)
              S[n2][reg] *= inv;
        }

        // PV in 32-key chunks; P row-major per q through own hb rows
        f4v o[2];
        { f4v zz = {0.f,0.f,0.f,0.f}; o[0] = zz; o[1] = zz; }
        #pragma unroll
        for (int c = 0; c < 2; ++c) {
          // store chunk c: keys c*32 + n2p*16 + quad*4 + reg -> cols of stripe
          #pragma unroll
          for (int n2p = 0; n2p < 2; ++n2p) {
            int n2 = 2*c + n2p;
            *(unsigned*)(hb + (row0 + l4)*136 + h*32 + n2p*16 + quad*4) =
                pack2(S[n2][0], S[n2][1]);
            *(unsigned*)(hb + (row0 + l4)*136 + h*32 + n2p*16 + quad*4 + 2) =
                pack2(S[n2][2], S[n2][3]);
          }
          // B-fragment: lane l4 = query col, regs = keys quad*8..+7 of chunk
          s8v pf = *(const s8v*)(hb + (row0 + l4)*136 + h*32 + quad*8);
          #pragma unroll
          for (int nt = 0; nt < 2; ++nt) {
            s8v av = *(const s8v*)(vtb + (h*32 + nt*16 + l4)*72 + c*32 + quad*8);
            o[nt] = MFMA16(av, pf, o[nt]);   // C[d][q]
          }
        }
        // O^T C-layout: lane l4 = q, regs = d = nt*16+quad*4+reg -> hb[q][d]
        #pragma unroll
        for (int nt = 0; nt < 2; ++nt) {
          *(unsigned*)(hb + (row0 + l4)*136 + h*32 + nt*16 + quad*4) =
              pack2(o[nt][0], o[nt][1]);
          *(unsigned*)(hb + (row0 + l4)*136 + h*32 + nt*16 + quad*4 + 2) =
              pack2(o[nt][2], o[nt][3]);
        }
      }
    }
    __syncthreads();

    // ---- output proj + residual (xr-indexed: keep unrolled) ----
    #pragma unroll
    for (int hh = 0; hh < 2; ++hh) {
      s8v ao[2][4];
      #pragma unroll
      for (int m2 = 0; m2 < 2; ++m2)
        #pragma unroll
        for (int k0 = 0; k0 < 4; ++k0)
          ao[m2][k0] = *(const s8v*)(hb + ((hh*2+m2)*16 + l4)*136 + k0*32 + quad*8);
      #pragma unroll
      for (int nt = 0; nt < 2; ++nt) {
        int c = wid*32 + nt*16 + l4;
        s8v bo[4];
        #pragma unroll
        for (int k0 = 0; k0 < 4; ++k0)
          bo[k0] = *(const s8v*)(outTl + c*128 + k0*32 + quad*8);
        float bias = outbl[c];
        #pragma unroll
        for (int m2 = 0; m2 < 2; ++m2) {
          int mt = hh*2 + m2;
          f4v a2 = {xr[mt][nt][0] + bias, xr[mt][nt][1] + bias,
                    xr[mt][nt][2] + bias, xr[mt][nt][3] + bias};
          #pragma unroll
          for (int k0 = 0; k0 < 4; ++k0)
            a2 = MFMA16(ao[m2][k0], bo[k0], a2);
          #pragma unroll
          for (int reg = 0; reg < 4; ++reg)
            xr[mt][nt][reg] = a2[reg];
        }
      }
    }

    ln_sub(xr, g2, bb2, red, hb, wid, quad, l4);   // LN2 -> hb

    // ---- MLP: weights loaded inside nt loops to cap arch pressure ----
    #pragma unroll 1
    for (int cc = 0; cc < 4; ++cc) {
      short* G = (cc & 1) ? vtb : kb;
      #pragma unroll 1
      for (int hh = 0; hh < 2; ++hh) {
        s8v afm[2][4];
        #pragma unroll
        for (int m2 = 0; m2 < 2; ++m2)
          #pragma unroll
          for (int k0 = 0; k0 < 4; ++k0)
            afm[m2][k0] = *(const s8v*)(hb + ((hh*2+m2)*16 + l4)*136 + k0*32 + quad*8);
        #pragma unroll
        for (int nt = 0; nt < 2; ++nt) {
          int jc = cc*128 + wid*32 + nt*16 + l4;
          s8v bm[4];
          #pragma unroll
          for (int k0 = 0; k0 < 4; ++k0)
            bm[k0] = *(const s8v*)(m1Tl + jc*128 + k0*32 + quad*8);
          float bias = m1bl[jc];
          #pragma unroll
          for (int m2 = 0; m2 < 2; ++m2) {
            f4v a2 = {bias, bias, bias, bias};
            #pragma unroll
            for (int k0 = 0; k0 < 4; ++k0)
              a2 = MFMA16(afm[m2][k0], bm[k0], a2);
            #pragma unroll
            for (int reg = 0; reg < 4; ++reg) {
              // gelu(v) = v * sigmoid(2*sqrt(2/pi)*(v + 0.044715 v^3))
              float v = a2[reg];
              float t = v * v;
              float u = fmaf(0.044715f, t, 1.0f);
              float w = v * u;
              float e = __expf(NGC2 * w);
              float gl = v * __builtin_amdgcn_rcpf(e + 1.0f);
              G[((hh*2+m2)*16 + quad*4 + reg)*136 + wid*32 + nt*16 + l4] = (short)f2bf(gl);
            }
          }
        }
      }
      __syncthreads();
      #pragma unroll
      for (int hh = 0; hh < 2; ++hh) {
        s8v at4[2][4];
        #pragma unroll
        for (int m2 = 0; m2 < 2; ++m2)
          #pragma unroll
          for (int k0 = 0; k0 < 4; ++k0)
            at4[m2][k0] = *(const s8v*)(G + ((hh*2+m2)*16 + l4)*136 + k0*32 + quad*8);
        #pragma unroll
        for (int nt = 0; nt < 2; ++nt) {
          int c = wid*32 + nt*16 + l4;
          s8v b2f[4];
          #pragma unroll
          for (int k0 = 0; k0 < 4; ++k0)
            b2f[k0] = *(const s8v*)(m2Tl + c*512 + cc*128 + k0*32 + quad*8);
          #pragma unroll
          for (int m2 = 0; m2 < 2; ++m2) {
            int mt = hh*2 + m2;
            f4v a2 = {xr[mt][nt][0], xr[mt][nt][1], xr[mt][nt][2], xr[mt][nt][3]};
            #pragma unroll
            for (int k0 = 0; k0 < 4; ++k0)
              a2 = MFMA16(at4[m2][k0], b2f[k0], a2);
            #pragma unroll
            for (int reg = 0; reg < 4; ++reg)
              xr[mt][nt][reg] = a2[reg];
          }
        }
      }
    }
    #pragma unroll
    for (int nt = 0; nt < 2; ++nt) {
      float b = m2bl[wid*32 + nt*16 + l4];
      #pragma unroll
      for (int mt = 0; mt < 4; ++mt)
        #pragma unroll
        for (int reg = 0; reg < 4; ++reg)
          xr[mt][nt][reg] += b;
    }
  }

  #pragma unroll
  for (int mt = 0; mt < 4; ++mt)
    #pragma unroll
    for (int nt = 0; nt < 2; ++nt)
      #pragma unroll
      for (int reg = 0; reg < 4; ++reg)
        xg[(mt*16 + quad*4 + reg)*128 + wid*32 + nt*16 + l4] = (short)f2bf(xr[mt][nt][reg]);
}

// ---------------- gather + GNN linear (bf16 in/out) ----------------
__global__ __launch_bounds__(256) void k_gnn(
    const short* __restrict__ feat, const int* __restrict__ nef,
    const int* __restrict__ corr, const int* __restrict__ centers,
    const int* __restrict__ nef2, const short* __restrict__ gnnT,
    short* __restrict__ out) {
  __shared__ __align__(16) short Ab[64 * 264];
  int n = blockIdx.x, t = threadIdx.x;
  int wid = t >> 6, lane = t & 63, l4 = lane & 15, quad = lane >> 4;
  int j = t >> 2, qq = t & 3;
  int e  = iclamp(nef[n*64 + j], 0, N_EDGE - 1);
  int ce = iclamp(corr[e], 0, N_EDGE - 1);
  size_t r1 = ((size_t)iclamp(centers[e],  0, N_NODES-1) * 64 + iclamp(nef2[e],  0, 63)) * 128;
  size_t r2 = ((size_t)iclamp(centers[ce], 0, N_NODES-1) * 64 + iclamp(nef2[ce], 0, 63)) * 128;
  {
    const s8v* p1 = (const s8v*)(feat + r1 + qq*32);
    const s8v* p2 = (const s8v*)(feat + r2 + qq*32);
    #pragma unroll
    for (int ii = 0; ii < 4; ++ii) {
      *(s8v*)(Ab + j*264 + qq*32 + ii*8)       = p1[ii];
      *(s8v*)(Ab + j*264 + 128 + qq*32 + ii*8) = p2[ii];
    }
  }
  __syncthreads();
  f4v acc[4][2];
  #pragma unroll
  for (int mt = 0; mt < 4; ++mt)
    #pragma unroll
    for (int nt = 0; nt < 2; ++nt) { f4v zz = {0.f,0.f,0.f,0.f}; acc[mt][nt] = zz; }
  #pragma unroll
  for (int k0 = 0; k0 < 8; ++k0) {
    s8v a[4];
    #pragma unroll
    for (int mt = 0; mt < 4; ++mt)
      a[mt] = *(const s8v*)(Ab + (mt*16 + l4)*264 + k0*32 + quad*8);
    #pragma unroll
    for (int nt = 0; nt < 2; ++nt) {
      s8v b = *(const s8v*)(gnnT + (wid*32 + nt*16 + l4)*256 + k0*32 + quad*8);
      #pragma unroll
      for (int mt = 0; mt < 4; ++mt)
        acc[mt][nt] = MFMA16(a[mt], b, acc[mt][nt]);
    }
  }
  #pragma unroll
  for (int mt = 0; mt < 4; ++mt)
    #pragma unroll
    for (int nt = 0; nt < 2; ++nt)
      #pragma unroll
      for (int reg = 0; reg < 4; ++reg)
        out[((size_t)n*64 + mt*16 + quad*4 + reg)*128 + wid*32 + nt*16 + l4] =
            (short)f2bf(acc[mt][nt][reg]);
}

// ---------------- final masked sum + head ----------------
__global__ __launch_bounds__(256) void k_final(
    const short* __restrict__ feat, const short* __restrict__ buf2,
    const float* __restrict__ rm, const float* __restrict__ lastw,
    const float* __restrict__ compw, const int* __restrict__ species,
    float* __restrict__ out) {
  __shared__ float part[4];
  int n = blockIdx.x, t = threadIdx.x;
  int wid = t >> 6, lane = t & 63;
  int j = t >> 2, qq = t & 3;
  size_t base = ((size_t)n*64 + j)*128 + qq*32;
  float s = 0.f;
  #pragma unroll
  for (int i = 0; i < 32; ++i)
    s += (bf2f(feat[base + i]) + bf2f(buf2[base + i])) * lastw[qq*32 + i];
  s += __shfl_xor(s, 1);
  s += __shfl_xor(s, 2);
  float v = (qq == 0) ? s * rm[n*64 + j] : 0.f;
  v += __shfl_xor(v, 4);  v += __shfl_xor(v, 8);
  v += __shfl_xor(v, 16); v += __shfl_xor(v, 32);
  if (lane == 0) part[wid] = v;
  __syncthreads();
  if (t == 0) out[n] = part[0] + part[1] + part[2] + part[3]
                       + compw[iclamp(species[n], 0, 3)];
}

// ---------------- host ----------------

extern "C" void kernel_launch(void* const* d_in, const int* in_sizes, int n_in,
                              void* d_out, int out_size, void* d_ws, size_t ws_size,
                              hipStream_t stream) {
  const float* ev      = (const float*)d_in[0];
  const float* cart    = (const float*)d_in[1];
  const float* cemb    = (const float*)d_in[2];
  const float* nemb    = (const float*)d_in[3];
  const float* comp    = (const float*)d_in[4];
  const float* gnnw    = (const float*)d_in[5];
  const float* lastw   = (const float*)d_in[6];
  const float* compw   = (const float*)d_in[7];
  const int*   species = (const int*)d_in[8];
  const int*   centers = (const int*)d_in[9];
  const int*   neighbors = (const int*)d_in[10];
  const int*   nef     = (const int*)d_in[11];
  /* d_in[12] = nef_mask: unused (masked slots are provably inert) */
  const int*   nef2    = (const int*)d_in[13];
  const int*   corr    = (const int*)d_in[14];

  // workspace layout (bytes)
  const size_t OFF_RM   = 0;           // 1,048,576
  const size_t OFF_FEAT = 1048576;     // 67,108,864 (bf16)
  const size_t OFF_BUF2 = 68157440;    // 67,108,864 (bf16)
  const size_t OFF_TABS = 135266304;   // 5,632
  const size_t OFF_WBF  = 135271936;   // 1,638,400
  const size_t NEED     = 136910336;
  if (ws_size < NEED) return;  // insufficient scratch: fail cleanly, not a fault

  char* ws = (char*)d_ws;
  float* rm   = (float*)(ws + OFF_RM);
  short* feat = (short*)(ws + OFF_FEAT);
  short* buf2 = (short*)(ws + OFF_BUF2);
  float* tabs = (float*)(ws + OFF_TABS);
  short* wbf  = (short*)(ws + OFF_WBF);

  short* t0q  = wbf + 0;       // 2x(384x128)
  short* t0o  = wbf + 98304;   // 2x(128x128)
  short* t0m1 = wbf + 131072;  // 2x(512x128)
  short* t0m2 = wbf + 262144;  // 2x(128x512)
  short* t1q  = wbf + 393216;
  short* t1o  = wbf + 491520;
  short* t1m1 = wbf + 524288;
  short* t1m2 = wbf + 655360;
  short* gnnT = wbf + 786432;  // 128x256

  hipMemsetAsync(rm, 0, 4096*64*sizeof(float), stream);

  k_tr<<<384, 256, 0, stream>>>((const float*)d_in[17], t0q,  2, 128, 384);
  k_tr<<<128, 256, 0, stream>>>((const float*)d_in[19], t0o,  2, 128, 128);
  k_tr<<<512, 256, 0, stream>>>((const float*)d_in[23], t0m1, 2, 128, 512);
  k_tr<<<512, 256, 0, stream>>>((const float*)d_in[25], t0m2, 2, 512, 128);
  k_tr<<<384, 256, 0, stream>>>((const float*)d_in[29], t1q,  2, 128, 384);
  k_tr<<<128, 256, 0, stream>>>((const float*)d_in[31], t1o,  2, 128, 128);
  k_tr<<<512, 256, 0, stream>>>((const float*)d_in[35], t1m1, 2, 128, 512);
  k_tr<<<512, 256, 0, stream>>>((const float*)d_in[37], t1m2, 2, 512, 128);
  k_tr<<<128, 256, 0, stream>>>(gnnw, gnnT, 1, 256, 128);
  k_tabs<<<6, 256, 0, stream>>>(cart, cemb, nemb, comp, tabs);
  k_rm<<<512, 256, 0, stream>>>(ev, centers, nef2, rm);
  k_enc<<<4096, 256, 0, stream>>>(ev, nef, centers, neighbors, species, tabs, feat);

  k_tf<<<4096, 256, 0, stream>>>(feat, rm,
      (const float*)d_in[15], (const float*)d_in[16], t0q, (const float*)d_in[18],
      t0o, (const float*)d_in[20], (const float*)d_in[21], (const float*)d_in[22],
      t0m1, (const float*)d_in[24], t0m2, (const float*)d_in[26]);

  k_gnn<<<4096, 256, 0, stream>>>(feat, nef, corr, centers, nef2, gnnT, buf2);

  k_tf<<<4096, 256, 0, stream>>>(buf2, rm,
      (const float*)d_in[27], (const float*)d_in[28], t1q, (const float*)d_in[30],
      t1o, (const float*)d_in[32], (const float*)d_in[33], (const float*)d_in[34],
      t1m1, (const float*)d_in[36], t1m2, (const float*)d_in[38]);

  k_final<<<4096, 256, 0, stream>>>(feat, buf2, rm, lastw, compw, species, (float*)d_out);
}